// Round 2
// baseline (994.101 us; speedup 1.0000x reference)
//
#include <hip/hip_runtime.h>
#include <math.h>

// Problem constants (fixed by the reference)
#define BATCH 4
#define SEQ   4096
#define EMB   512
#define PADW  128
#define SPAD  (SEQ + 2*PADW)   // 4352 padded sequence
#define WIN   (3*PADW)         // 384-key window per 128-query block
#define QC    8                // queries per attention workgroup

static constexpr float SCALE = 0.04419417382415922f; // 1/sqrt(512)

// ---------------------------------------------------------------------------
// Kernel 1: fused QKV projection over the PADDED sequence.
//   For ext row t (0..SPAD): row = (P<=t<S+P) ? x[t-P] : 0
//   q_ext[t] = row @ Wq + bq   (only interior rows used later, pads wasted 1.5%)
//   k[t]     = row @ Wk + bk
//   v[t]     = row @ Wv + bv
// Classic f32 SGEMM: 128x64 tile, 256 threads, 8x4 micro-tile, BK=16.
// grid = (SPAD/128, EMB/64, BATCH*3)
// ---------------------------------------------------------------------------
#define BM 128
#define BN 64
#define BK 16

__global__ __launch_bounds__(256) void proj_kernel(
    const float* __restrict__ x,
    const float* __restrict__ Wq, const float* __restrict__ bq,
    const float* __restrict__ Wk, const float* __restrict__ bk,
    const float* __restrict__ Wv, const float* __restrict__ bv,
    float* __restrict__ qx, float* __restrict__ kx, float* __restrict__ vx)
{
    const int mt = blockIdx.x;            // M tile (ext rows)
    const int nt = blockIdx.y;            // N tile (output cols)
    const int b  = blockIdx.z / 3;
    const int w  = blockIdx.z % 3;        // 0=q 1=k 2=v
    const float* Wm = (w == 0) ? Wq : (w == 1) ? Wk : Wv;
    const float* bm = (w == 0) ? bq : (w == 1) ? bk : bv;
    float* om       = (w == 0) ? qx : (w == 1) ? kx : vx;

    __shared__ float As[BK][BM];          // A-tile stored transposed
    __shared__ float Bs[BK][BN];

    const int tid = threadIdx.x;
    const int ty  = tid >> 4;             // 0..15 -> rows r0..r0+7
    const int tx  = tid & 15;             // 0..15 -> cols c0..c0+3
    const int r0  = ty * 8;
    const int c0  = tx * 4;

    const int row_base = mt * BM;         // ext-row base of tile
    const int col_base = nt * BN;

    float acc[8][4];
#pragma unroll
    for (int i = 0; i < 8; ++i)
#pragma unroll
        for (int j = 0; j < 4; ++j) acc[i][j] = 0.f;

    for (int kt = 0; kt < EMB; kt += BK) {
        // A tile: 128 rows x 16 cols = 512 float4, 2 per thread, zero-guarded pads
#pragma unroll
        for (int i = 0; i < 2; ++i) {
            int f   = tid + 256 * i;
            int row = f >> 2;
            int c4  = (f & 3) * 4;
            int xr  = row_base + row - PADW;
            float4 val = make_float4(0.f, 0.f, 0.f, 0.f);
            if (xr >= 0 && xr < SEQ)
                val = *reinterpret_cast<const float4*>(
                    &x[((size_t)b * SEQ + xr) * EMB + kt + c4]);
            As[c4 + 0][row] = val.x;
            As[c4 + 1][row] = val.y;
            As[c4 + 2][row] = val.z;
            As[c4 + 3][row] = val.w;
        }
        // B tile: 16 rows x 64 cols = 256 float4, 1 per thread (coalesced)
        {
            int row = tid >> 4;
            int c4  = (tid & 15) * 4;
            float4 val = *reinterpret_cast<const float4*>(
                &Wm[(size_t)(kt + row) * EMB + col_base + c4]);
            *reinterpret_cast<float4*>(&Bs[row][c4]) = val;
        }
        __syncthreads();
#pragma unroll
        for (int kk = 0; kk < BK; ++kk) {
            float a[8], bb[4];
#pragma unroll
            for (int i = 0; i < 8; ++i) a[i] = As[kk][r0 + i];
#pragma unroll
            for (int j = 0; j < 4; ++j) bb[j] = Bs[kk][c0 + j];
#pragma unroll
            for (int i = 0; i < 8; ++i)
#pragma unroll
                for (int j = 0; j < 4; ++j) acc[i][j] += a[i] * bb[j];
        }
        __syncthreads();
    }

    float bias[4];
#pragma unroll
    for (int j = 0; j < 4; ++j) bias[j] = bm[col_base + c0 + j];
#pragma unroll
    for (int i = 0; i < 8; ++i) {
        int row = row_base + r0 + i;
        float4 o;
        o.x = acc[i][0] + bias[0];
        o.y = acc[i][1] + bias[1];
        o.z = acc[i][2] + bias[2];
        o.w = acc[i][3] + bias[3];
        *reinterpret_cast<float4*>(
            &om[((size_t)b * SPAD + row) * EMB + col_base + c0]) = o;
    }
}

// ---------------------------------------------------------------------------
// Kernel 2: banded local attention.
// One workgroup = 8 consecutive queries. Key window = 384 ext rows starting at
// the query's 128-block. Band per query qi (pos within block): keys [qi, qi+256].
// pm==0 keys inside band get -1e9 (NOT excluded); out-of-band excluded (-inf).
// grid = (SEQ/QC, BATCH), 256 threads.
// ---------------------------------------------------------------------------
__global__ __launch_bounds__(256) void attn_kernel(
    const float* __restrict__ qx,   // [B,SPAD,E]
    const float* __restrict__ kx,
    const float* __restrict__ vx,
    const int*   __restrict__ mask, // [B,S]
    float* __restrict__ out)        // [B,S,E]
{
    const int cq = blockIdx.x;
    const int b  = blockIdx.y;
    const int s0 = cq * QC;          // first query (0..S-8)
    const int nb = s0 / PADW;        // 128-block index
    const int o  = s0 % PADW;        // offset inside block (multiple of 8)
    const int t0 = nb * PADW;        // ext-row base of key window

    __shared__ float Ks[WIN][33];    // stride 33 -> conflict-free column reads
    __shared__ float Qs[QC][32];
    __shared__ float Sc[QC][WIN];    // scores, then attention weights
    __shared__ float Pm[WIN];

    const int tid = threadIdx.x;

    // key-side mask (pads are UNMASKED = 1)
    for (int k = tid; k < WIN; k += 256) {
        int t = t0 + k;
        float pm = 1.f;
        if (t >= PADW && t < SEQ + PADW) pm = (float)mask[b * SEQ + (t - PADW)];
        Pm[k] = pm;
    }

    // ---- phase 1: raw scores  Sc[q][k] = q_row . k_row  (e-tiled) ----
    float acc0[QC], acc1[QC];
#pragma unroll
    for (int q = 0; q < QC; ++q) { acc0[q] = 0.f; acc1[q] = 0.f; }
    const int k0   = tid;
    const int k1   = tid + 256;
    const bool has1 = (tid < WIN - 256);   // 128 threads carry a 2nd key

    for (int et = 0; et < EMB; et += 32) {
        {   // Q slice: 8x32 = 256 elements
            int q = tid >> 5, e = tid & 31;
            Qs[q][e] = qx[((size_t)b * SPAD + PADW + s0 + q) * EMB + et + e];
        }
        // K slice: 384x32 = 3072 float4, 12 per thread (coalesced rows)
#pragma unroll
        for (int i = 0; i < 12; ++i) {
            int f   = tid + 256 * i;
            int row = f >> 3;
            int c4  = (f & 7) * 4;
            float4 val = *reinterpret_cast<const float4*>(
                &kx[((size_t)b * SPAD + t0 + row) * EMB + et + c4]);
            Ks[row][c4 + 0] = val.x;
            Ks[row][c4 + 1] = val.y;
            Ks[row][c4 + 2] = val.z;
            Ks[row][c4 + 3] = val.w;
        }
        __syncthreads();
#pragma unroll
        for (int e = 0; e < 32; ++e) {
            float kv0 = Ks[k0][e];
            float kv1 = has1 ? Ks[k1][e] : 0.f;
#pragma unroll
            for (int q = 0; q < QC; ++q) {
                float qv = Qs[q][e];         // broadcast read
                acc0[q] += qv * kv0;
                acc1[q] += qv * kv1;
            }
        }
        __syncthreads();
    }
#pragma unroll
    for (int q = 0; q < QC; ++q) {
        Sc[q][k0] = acc0[q];
        if (has1) Sc[q][k1] = acc1[q];
    }
    __syncthreads();

    // ---- phase 2: masked banded softmax (32 lanes per query row) ----
    {
        const int q  = tid >> 5;        // 0..7
        const int j  = tid & 31;
        const int oq = o + q;           // band = [oq, oq+256]
        float vals[12];
        float m = -INFINITY;
#pragma unroll
        for (int i = 0; i < 12; ++i) {
            int k = j + 32 * i;
            float v = -INFINITY;
            if (k >= oq && k <= oq + 2 * PADW)
                v = (Pm[k] == 0.f) ? -1e9f : Sc[q][k] * SCALE;
            vals[i] = v;
            m = fmaxf(m, v);
        }
#pragma unroll
        for (int d = 16; d >= 1; d >>= 1) m = fmaxf(m, __shfl_xor(m, d, 32));
        float l = 0.f;
#pragma unroll
        for (int i = 0; i < 12; ++i) {
            float p = (vals[i] == -INFINITY) ? 0.f : __expf(vals[i] - m);
            vals[i] = p;
            l += p;
        }
#pragma unroll
        for (int d = 16; d >= 1; d >>= 1) l += __shfl_xor(l, d, 32);
        const float inv = 1.f / l;
#pragma unroll
        for (int i = 0; i < 12; ++i) Sc[q][j + 32 * i] = vals[i] * inv;
    }
    __syncthreads();

    // ---- phase 3: O = A @ V over the union band [o, o+263] ----
    const int e0 = tid * 2;             // each thread owns 2 output cols
    float oa[QC][2];
#pragma unroll
    for (int q = 0; q < QC; ++q) { oa[q][0] = 0.f; oa[q][1] = 0.f; }
    const int kend = o + (QC - 1) + 2 * PADW;   // inclusive
    for (int k = o; k <= kend; ++k) {
        const float2 vv = *reinterpret_cast<const float2*>(
            &vx[((size_t)b * SPAD + t0 + k) * EMB + e0]);
#pragma unroll
        for (int q = 0; q < QC; ++q) {
            float a = Sc[q][k];          // broadcast read
            oa[q][0] += a * vv.x;
            oa[q][1] += a * vv.y;
        }
    }
    // epilogue: zero rows whose query mask == 0
#pragma unroll
    for (int q = 0; q < QC; ++q) {
        int s = s0 + q;
        float mq = (mask[b * SEQ + s] != 0) ? 1.f : 0.f;
        float2 o2 = make_float2(oa[q][0] * mq, oa[q][1] * mq);
        *reinterpret_cast<float2*>(&out[((size_t)b * SEQ + s) * EMB + e0]) = o2;
    }
}

// ---------------------------------------------------------------------------
extern "C" void kernel_launch(void* const* d_in, const int* in_sizes, int n_in,
                              void* d_out, int out_size, void* d_ws, size_t ws_size,
                              hipStream_t stream)
{
    const float* x    = (const float*)d_in[0];
    const int*   mask = (const int*)  d_in[1];
    const float* Wq   = (const float*)d_in[2];
    const float* bq   = (const float*)d_in[3];
    const float* Wk   = (const float*)d_in[4];
    const float* bk   = (const float*)d_in[5];
    const float* Wv   = (const float*)d_in[6];
    const float* bv   = (const float*)d_in[7];
    float* out = (float*)d_out;

    float* qx = (float*)d_ws;                       // [B,SPAD,E] each
    float* kx = qx + (size_t)BATCH * SPAD * EMB;
    float* vx = kx + (size_t)BATCH * SPAD * EMB;    // total ~107 MB

    dim3 pg(SPAD / BM, EMB / BN, BATCH * 3);
    proj_kernel<<<pg, 256, 0, stream>>>(x, Wq, bq, Wk, bk, Wv, bv, qx, kx, vx);

    dim3 ag(SEQ / QC, BATCH);
    attn_kernel<<<ag, 256, 0, stream>>>(qx, kx, vx, mask, out);
}

// Round 3
// 318.382 us; speedup vs baseline: 3.1223x; 3.1223x over previous
//
#include <hip/hip_runtime.h>
#include <math.h>
#include <stdint.h>

// Problem constants
#define BATCH 4
#define SEQ   4096
#define EMB   512
#define PADW  128
#define SPAD  (SEQ + 2*PADW)   // 4352
#define KS3   (3*EMB)          // 1536 = split-K (hi,hi,lo)x(hi,lo,hi)
#define WIN   (3*PADW)         // 384 keys per window

static constexpr float SCALE = 0.04419417382415922f; // 1/sqrt(512)

typedef __attribute__((ext_vector_type(8))) short bf16x8;
typedef __attribute__((ext_vector_type(4))) short s16x4;
typedef __attribute__((ext_vector_type(4))) float f32x4;

__device__ __forceinline__ unsigned short f2bf(float x) { // RNE f32->bf16
  union { float f; uint32_t u; } v; v.f = x;
  return (unsigned short)((v.u + 0x7FFFu + ((v.u >> 16) & 1u)) >> 16);
}
__device__ __forceinline__ float bf2f(unsigned short h) {
  union { uint32_t u; float f; } v; v.u = ((uint32_t)h) << 16;
  return v.f;
}
__device__ __forceinline__ void gload16(const void* g, void* lds) {
  __builtin_amdgcn_global_load_lds(
      (const __attribute__((address_space(1))) uint32_t*)g,
      (__attribute__((address_space(3))) uint32_t*)lds, 16, 0, 0);
}
// LDS tile rows of 128B (8 x 16B slots), slot XOR-swizzled by (row&7).
__device__ __forceinline__ bf16x8 frag64(const unsigned short* base, int row, int slot) {
  return *(const bf16x8*)((const char*)base + row * 128 + ((slot ^ (row & 7)) << 4));
}

// ---------------------------------------------------------------------------
// x [B,SEQ,512] f32 -> xs [B,SEQ,1536] bf16 (hi, hi, lo)
// ---------------------------------------------------------------------------
__global__ __launch_bounds__(256) void convert_x(const float* __restrict__ x,
                                                 unsigned short* __restrict__ xs) {
  size_t i = (size_t)blockIdx.x * 256 + threadIdx.x;  // one per 4 floats
  if (i >= (size_t)BATCH * SEQ * (EMB / 4)) return;
  size_t row = i >> 7;
  int c4 = ((int)i & 127) * 4;
  float4 v = *(const float4*)&x[row * EMB + c4];
  float vv[4] = {v.x, v.y, v.z, v.w};
  s16x4 h, l;
#pragma unroll
  for (int j = 0; j < 4; ++j) {
    unsigned short hh = f2bf(vv[j]);
    h[j] = (short)hh;
    l[j] = (short)f2bf(vv[j] - bf2f(hh));
  }
  size_t base = row * KS3 + c4;
  *(s16x4*)&xs[base] = h;
  *(s16x4*)&xs[base + 512] = h;
  *(s16x4*)&xs[base + 1024] = l;
}

// ---------------------------------------------------------------------------
// W [512,512] f32 (x3) -> wt [3, 512 n, 1536 k'] bf16, k'-bands (hi, lo, hi),
// TRANSPOSED so GEMM B-fragments read contiguous k'.
// ---------------------------------------------------------------------------
__global__ __launch_bounds__(256) void convert_w(const float* __restrict__ Wq,
                                                 const float* __restrict__ Wk,
                                                 const float* __restrict__ Wv,
                                                 unsigned short* __restrict__ wt) {
  const int w = blockIdx.z;
  const float* W = (w == 0) ? Wq : (w == 1) ? Wk : Wv;
  const int kt = blockIdx.x * 64, nt = blockIdx.y * 64;
  __shared__ float T[64][65];
  const int tid = threadIdx.x;
  {
    int r = tid >> 4, c4 = (tid & 15) * 4;
#pragma unroll
    for (int i = 0; i < 4; ++i) {
      float4 v = *(const float4*)&W[(size_t)(kt + r + 16 * i) * EMB + nt + c4];
      T[r + 16 * i][c4 + 0] = v.x;
      T[r + 16 * i][c4 + 1] = v.y;
      T[r + 16 * i][c4 + 2] = v.z;
      T[r + 16 * i][c4 + 3] = v.w;
    }
  }
  __syncthreads();
  {
    int n = tid >> 2, k0 = (tid & 3) * 16;
    __align__(16) unsigned short hb[16], lb[16];
#pragma unroll
    for (int j = 0; j < 16; ++j) {
      float v = T[k0 + j][n];
      unsigned short h = f2bf(v);
      hb[j] = h;
      lb[j] = f2bf(v - bf2f(h));
    }
    size_t base = ((size_t)w * EMB + nt + n) * KS3;
    *(bf16x8*)&wt[base + kt + k0]            = *(bf16x8*)&hb[0];
    *(bf16x8*)&wt[base + kt + k0 + 8]        = *(bf16x8*)&hb[8];
    *(bf16x8*)&wt[base + 512 + kt + k0]      = *(bf16x8*)&lb[0];
    *(bf16x8*)&wt[base + 512 + kt + k0 + 8]  = *(bf16x8*)&lb[8];
    *(bf16x8*)&wt[base + 1024 + kt + k0]     = *(bf16x8*)&hb[0];
    *(bf16x8*)&wt[base + 1024 + kt + k0 + 8] = *(bf16x8*)&hb[8];
  }
}

// ---------------------------------------------------------------------------
// Projection GEMM (split-K bf16 MFMA): out = ext(x) @ W + b for q,k,v.
// 128x128 tile, 4 waves, BK=64, global_load_lds(16) with XOR-swizzled source.
// Epilogue writes q/k in split layouts for the attention GEMMs, v as bf16.
// grid (34, 4, 12): M-tiles over SPAD (tiles 0,33 are all-pad -> bias only).
// ---------------------------------------------------------------------------
__global__ __launch_bounds__(256) void proj_kernel(
    const unsigned short* __restrict__ xs,  // [B,SEQ,1536]
    const unsigned short* __restrict__ wt,  // [3,512,1536]
    const float* __restrict__ bq, const float* __restrict__ bk, const float* __restrict__ bv,
    unsigned short* __restrict__ qs,   // [B,SPAD,1536] (qh qh ql)
    unsigned short* __restrict__ ksb,  // [B,SPAD,1536] (kh kl kh)
    unsigned short* __restrict__ vs)   // [B,SPAD,512]
{
  const int mt = blockIdx.x, nt = blockIdx.y;
  const int b = blockIdx.z / 3, w = blockIdx.z % 3;
  const float* bias = (w == 0) ? bq : (w == 1) ? bk : bv;
  const int tid = threadIdx.x, lane = tid & 63, wid = tid >> 6;
  const int t0 = mt * 128, n0 = nt * 128;

  if (mt == 0 || mt == 33) {  // pad rows: Linear(0) = bias
    for (int i = tid; i < 128 * 128; i += 256) {
      int r = i >> 7, n = n0 + (i & 127), t = t0 + r;
      float o = bias[n];
      unsigned short h = f2bf(o), l = f2bf(o - bf2f(h));
      if (w == 0) { size_t base = ((size_t)b * SPAD + t) * KS3; qs[base + n] = h; qs[base + 512 + n] = h; qs[base + 1024 + n] = l; }
      else if (w == 1) { size_t base = ((size_t)b * SPAD + t) * KS3; ksb[base + n] = h; ksb[base + 512 + n] = l; ksb[base + 1024 + n] = h; }
      else { vs[((size_t)b * SPAD + t) * EMB + n] = h; }
    }
    return;
  }

  __shared__ unsigned short At[128 * 64];  // [128 m][64 k] swz
  __shared__ unsigned short Bt[128 * 64];  // [128 n][64 k] swz
  f32x4 acc[4][4];
#pragma unroll
  for (int i = 0; i < 4; ++i)
#pragma unroll
    for (int j = 0; j < 4; ++j) acc[i][j] = (f32x4){0.f, 0.f, 0.f, 0.f};

  const int xr0 = (mt - 1) * 128;
  const int wm = wid >> 1, wn = wid & 1;

  for (int kt = 0; kt < KS3; kt += 64) {
#pragma unroll
    for (int i = 0; i < 4; ++i) {  // A tile: 1024 chunks
      int c = wid * 256 + i * 64 + lane;
      int m = c >> 3, sl = (c & 7) ^ (m & 7);
      gload16(xs + ((size_t)b * SEQ + xr0 + m) * KS3 + kt + sl * 8,
              (char*)At + (wid * 256 + i * 64) * 16);
    }
#pragma unroll
    for (int i = 0; i < 4; ++i) {  // B tile
      int c = wid * 256 + i * 64 + lane;
      int n = c >> 3, sl = (c & 7) ^ (n & 7);
      gload16(wt + ((size_t)w * EMB + n0 + n) * KS3 + kt + sl * 8,
              (char*)Bt + (wid * 256 + i * 64) * 16);
    }
    __syncthreads();
#pragma unroll
    for (int kk = 0; kk < 2; ++kk) {
      bf16x8 af[4], bfr[4];
#pragma unroll
      for (int f = 0; f < 4; ++f)
        af[f] = frag64(At, wm * 64 + f * 16 + (lane & 15), kk * 4 + (lane >> 4));
#pragma unroll
      for (int f = 0; f < 4; ++f)
        bfr[f] = frag64(Bt, wn * 64 + f * 16 + (lane & 15), kk * 4 + (lane >> 4));
#pragma unroll
      for (int fm = 0; fm < 4; ++fm)
#pragma unroll
        for (int fn = 0; fn < 4; ++fn)
          acc[fm][fn] = __builtin_amdgcn_mfma_f32_16x16x32_bf16(af[fm], bfr[fn], acc[fm][fn], 0, 0, 0);
    }
    __syncthreads();
  }

#pragma unroll
  for (int fm = 0; fm < 4; ++fm) {
    int t = t0 + wm * 64 + fm * 16 + ((lane >> 4) << 2);
#pragma unroll
    for (int fn = 0; fn < 4; ++fn) {
      int n = n0 + wn * 64 + fn * 16 + (lane & 15);
      float bsv = bias[n];
#pragma unroll
      for (int r = 0; r < 4; ++r) {
        float o = acc[fm][fn][r] + bsv;
        unsigned short h = f2bf(o), l = f2bf(o - bf2f(h));
        size_t tt = (size_t)b * SPAD + (t + r);
        if (w == 0) { size_t base = tt * KS3; qs[base + n] = h; qs[base + 512 + n] = h; qs[base + 1024 + n] = l; }
        else if (w == 1) { size_t base = tt * KS3; ksb[base + n] = h; ksb[base + 512 + n] = l; ksb[base + 1024 + n] = h; }
        else { vs[tt * EMB + n] = h; }
      }
    }
  }
}

// ---------------------------------------------------------------------------
// vs [B,SPAD,512] -> vt [B,512,SPAD]  (bf16 transpose for PV B-fragments)
// ---------------------------------------------------------------------------
__global__ __launch_bounds__(256) void transpose_v(const unsigned short* __restrict__ vs,
                                                   unsigned short* __restrict__ vt) {
  const int b = blockIdx.z, tt = blockIdx.x * 64, et = blockIdx.y * 64;
  __shared__ unsigned short T[64][80];
  const int tid = threadIdx.x;
#pragma unroll
  for (int i = 0; i < 2; ++i) {
    int c = tid + 256 * i;
    int r = c >> 3, co = (c & 7) * 8;
    *(bf16x8*)&T[r][co] =
        *(const bf16x8*)&vs[((size_t)b * SPAD + tt + r) * EMB + et + co];
  }
  __syncthreads();
  int e = tid >> 2, sg = (tid & 3) * 16;
  __align__(16) unsigned short buf[16];
#pragma unroll
  for (int j = 0; j < 16; ++j) buf[j] = T[sg + j][e];
  size_t obase = ((size_t)b * EMB + et + e) * SPAD + tt + sg;
  *(bf16x8*)&vt[obase] = *(bf16x8*)&buf[0];
  *(bf16x8*)&vt[obase + 8] = *(bf16x8*)&buf[8];
}

// ---------------------------------------------------------------------------
// Banded attention, MFMA. One wg = 64 queries, 8 waves (512 thr).
// Phase A: S^T[384,64] = K'[384,1536] . Q'^T (split-K bf16) -> regs
// Phase B: mask + softmax (wave shuffle + LDS cross-wave), P -> LDS bf16
// Phase C: O[64,512] = P[64,384] . V[384,512], V staged from vt transposed.
// grid (SEQ/64, B).
// ---------------------------------------------------------------------------
__global__ __launch_bounds__(512) void attn_kernel(
    const unsigned short* __restrict__ qs,
    const unsigned short* __restrict__ ksp,
    const unsigned short* __restrict__ vt,
    const int* __restrict__ mask,
    float* __restrict__ out) {
  const int b = blockIdx.y;
  const int s0 = blockIdx.x * 64;
  const int nb = s0 >> 7, o = s0 & 127;  // o in {0, 64}
  const int t0 = nb * 128;
  const int tid = threadIdx.x, lane = tid & 63, wid = tid >> 6;

  __shared__ __align__(16) char smem[88 * 1024];
  unsigned short* Kt = (unsigned short*)smem;                 // [384][64] swz / later P [64][384] swz
  unsigned short* Qt = (unsigned short*)(smem + 48 * 1024);   // [64][64] swz
  float* red  = (float*)(smem + 48 * 1024);                   // [8][64] (after phase A)
  float* red2 = (float*)(smem + 48 * 1024 + 2048);
  float* invl = (float*)(smem + 48 * 1024 + 4096);            // [64]
  float* Pm   = (float*)(smem + 48 * 1024 + 4352);            // [384]
  unsigned short* Vt = (unsigned short*)(smem + 56 * 1024);   // [512][32] swz

  // ---- phase A: S^T = K'.Q'^T ----
  f32x4 accS[3][4];
#pragma unroll
  for (int i = 0; i < 3; ++i)
#pragma unroll
    for (int j = 0; j < 4; ++j) accS[i][j] = (f32x4){0.f, 0.f, 0.f, 0.f};

  for (int kt = 0; kt < KS3; kt += 64) {
#pragma unroll
    for (int i = 0; i < 6; ++i) {  // K' tile: 3072 chunks
      int c = wid * 384 + i * 64 + lane;
      int r = c >> 3, sl = (c & 7) ^ (r & 7);
      gload16(ksp + ((size_t)b * SPAD + t0 + r) * KS3 + kt + sl * 8,
              (char*)Kt + (wid * 384 + i * 64) * 16);
    }
    {  // Q' tile: 512 chunks
      int c = wid * 64 + lane;
      int r = c >> 3, sl = (c & 7) ^ (r & 7);
      gload16(qs + ((size_t)b * SPAD + PADW + s0 + r) * KS3 + kt + sl * 8,
              (char*)Qt + (wid * 64) * 16);
    }
    __syncthreads();
#pragma unroll
    for (int kk = 0; kk < 2; ++kk) {
      bf16x8 af[3], bfq[4];
#pragma unroll
      for (int f = 0; f < 3; ++f)
        af[f] = frag64(Kt, wid * 48 + f * 16 + (lane & 15), kk * 4 + (lane >> 4));
#pragma unroll
      for (int f = 0; f < 4; ++f)
        bfq[f] = frag64(Qt, f * 16 + (lane & 15), kk * 4 + (lane >> 4));
#pragma unroll
      for (int fk = 0; fk < 3; ++fk)
#pragma unroll
        for (int fq = 0; fq < 4; ++fq)
          accS[fk][fq] = __builtin_amdgcn_mfma_f32_16x16x32_bf16(af[fk], bfq[fq], accS[fk][fq], 0, 0, 0);
    }
    __syncthreads();
  }

  // key-side mask (pads unmasked = 1)
  for (int k = tid; k < WIN; k += 512) {
    int t = t0 + k;
    Pm[k] = (t >= PADW && t < SEQ + PADW) ? (float)mask[(size_t)b * SEQ + (t - PADW)] : 1.f;
  }
  __syncthreads();

  // ---- phase B: mask + softmax ----
  float mx[4] = {-INFINITY, -INFINITY, -INFINITY, -INFINITY};
#pragma unroll
  for (int fk = 0; fk < 3; ++fk)
#pragma unroll
    for (int fq = 0; fq < 4; ++fq)
#pragma unroll
      for (int r = 0; r < 4; ++r) {
        int k = wid * 48 + fk * 16 + ((lane >> 4) << 2) + r;
        int p = o + fq * 16 + (lane & 15);  // query pos in block
        float v;
        if (k < p || k > p + 2 * PADW) v = -INFINITY;                 // band
        else v = (Pm[k] == 0.f) ? -1e9f : accS[fk][fq][r] * SCALE;    // pm mask
        accS[fk][fq][r] = v;
        mx[fq] = fmaxf(mx[fq], v);
      }
#pragma unroll
  for (int fq = 0; fq < 4; ++fq) {
    mx[fq] = fmaxf(mx[fq], __shfl_xor(mx[fq], 16));
    mx[fq] = fmaxf(mx[fq], __shfl_xor(mx[fq], 32));
  }
  if (lane < 16) {
#pragma unroll
    for (int fq = 0; fq < 4; ++fq) red[wid * 64 + fq * 16 + lane] = mx[fq];
  }
  __syncthreads();
  float M[4];
#pragma unroll
  for (int fq = 0; fq < 4; ++fq) {
    float m = -INFINITY;
#pragma unroll
    for (int ww = 0; ww < 8; ++ww) m = fmaxf(m, red[ww * 64 + fq * 16 + (lane & 15)]);
    M[fq] = m;
  }
  float sm[4] = {0.f, 0.f, 0.f, 0.f};
#pragma unroll
  for (int fk = 0; fk < 3; ++fk)
#pragma unroll
    for (int fq = 0; fq < 4; ++fq)
#pragma unroll
      for (int r = 0; r < 4; ++r) {
        float pv = __expf(accS[fk][fq][r] - M[fq]);
        accS[fk][fq][r] = pv;
        sm[fq] += pv;
      }
#pragma unroll
  for (int fq = 0; fq < 4; ++fq) {
    sm[fq] += __shfl_xor(sm[fq], 16);
    sm[fq] += __shfl_xor(sm[fq], 32);
  }
  if (lane < 16) {
#pragma unroll
    for (int fq = 0; fq < 4; ++fq) red2[wid * 64 + fq * 16 + lane] = sm[fq];
  }
  __syncthreads();
  {
    float L[4];
#pragma unroll
    for (int fq = 0; fq < 4; ++fq) {
      float s = 0.f;
#pragma unroll
      for (int ww = 0; ww < 8; ++ww) s += red2[ww * 64 + fq * 16 + (lane & 15)];
      L[fq] = s;
    }
    if (wid == 0 && lane < 16) {
#pragma unroll
      for (int fq = 0; fq < 4; ++fq) invl[fq * 16 + lane] = 1.f / L[fq];
    }
  }
  // write P (bf16, unnormalized) to LDS: [64 q][384 k], 16B-slot XOR (q&7)
#pragma unroll
  for (int fk = 0; fk < 3; ++fk)
#pragma unroll
    for (int fq = 0; fq < 4; ++fq) {
      int k0 = wid * 48 + fk * 16 + ((lane >> 4) << 2);
      int q = fq * 16 + (lane & 15);
      s16x4 pk;
      pk[0] = (short)f2bf(accS[fk][fq][0]);
      pk[1] = (short)f2bf(accS[fk][fq][1]);
      pk[2] = (short)f2bf(accS[fk][fq][2]);
      pk[3] = (short)f2bf(accS[fk][fq][3]);
      int sl = k0 >> 3;
      *(s16x4*)((char*)Kt + q * 768 + (((sl ^ (q & 7))) << 4) + ((k0 & 7) << 1)) = pk;
    }
  __syncthreads();

  // ---- phase C: O = P.V ----
  f32x4 accO[4][4];
#pragma unroll
  for (int i = 0; i < 4; ++i)
#pragma unroll
    for (int j = 0; j < 4; ++j) accO[i][j] = (f32x4){0.f, 0.f, 0.f, 0.f};

  for (int kb = 0; kb < WIN; kb += 32) {
#pragma unroll
    for (int i = 0; i < 4; ++i) {  // Vt tile [512][32]: 2048 chunks
      int c = wid * 256 + i * 64 + lane;
      int e = c >> 2, sl = (c & 3) ^ (e & 3);
      gload16(vt + ((size_t)b * EMB + e) * SPAD + t0 + kb + sl * 8,
              (char*)Vt + (wid * 256 + i * 64) * 16);
    }
    __syncthreads();
    bf16x8 pa[4], vb[4];
#pragma unroll
    for (int fq = 0; fq < 4; ++fq) {
      int q = fq * 16 + (lane & 15);
      int sl = (kb + ((lane >> 4) << 3)) >> 3;
      pa[fq] = *(const bf16x8*)((const char*)Kt + q * 768 + ((sl ^ (q & 7)) << 4));
    }
#pragma unroll
    for (int fe = 0; fe < 4; ++fe) {
      int e = wid * 64 + fe * 16 + (lane & 15);
      int sl = (lane >> 4) ^ (e & 3);
      vb[fe] = *(const bf16x8*)((const char*)Vt + e * 64 + (sl << 4));
    }
#pragma unroll
    for (int fq = 0; fq < 4; ++fq)
#pragma unroll
      for (int fe = 0; fe < 4; ++fe)
        accO[fq][fe] = __builtin_amdgcn_mfma_f32_16x16x32_bf16(pa[fq], vb[fe], accO[fq][fe], 0, 0, 0);
    __syncthreads();
  }

  // epilogue: normalize by 1/l, zero masked queries
#pragma unroll
  for (int fq = 0; fq < 4; ++fq)
#pragma unroll
    for (int r = 0; r < 4; ++r) {
      int q = fq * 16 + ((lane >> 4) << 2) + r;
      float sc = invl[q] * ((Pm[PADW + o + q] != 0.f) ? 1.f : 0.f);
#pragma unroll
      for (int fe = 0; fe < 4; ++fe) {
        int e = wid * 64 + fe * 16 + (lane & 15);
        out[((size_t)b * SEQ + s0 + q) * EMB + e] = accO[fq][fe][r] * sc;
      }
    }
}

// ---------------------------------------------------------------------------
extern "C" void kernel_launch(void* const* d_in, const int* in_sizes, int n_in,
                              void* d_out, int out_size, void* d_ws, size_t ws_size,
                              hipStream_t stream) {
  const float* x  = (const float*)d_in[0];
  const int* mask = (const int*)d_in[1];
  const float* Wq = (const float*)d_in[2];
  const float* bq = (const float*)d_in[3];
  const float* Wk = (const float*)d_in[4];
  const float* bk = (const float*)d_in[5];
  const float* Wv = (const float*)d_in[6];
  const float* bv = (const float*)d_in[7];
  float* out = (float*)d_out;

  char* ws = (char*)d_ws;
  unsigned short* xs  = (unsigned short*)ws;               // 50,331,648 B [B,SEQ,1536]
  unsigned short* vt  = (unsigned short*)ws;               // 17,825,792 B overlay (xs dead when written)
  unsigned short* wt  = (unsigned short*)(ws + 50331648);  //  4,718,592 B [3,512,1536]
  unsigned short* qs  = (unsigned short*)(ws + 55050240);  // 53,477,376 B [B,SPAD,1536]
  unsigned short* ksb = (unsigned short*)(ws + 108527616); // 53,477,376 B [B,SPAD,1536]
  unsigned short* vs  = (unsigned short*)(ws + 162004992); // 17,825,792 B [B,SPAD,512] -> total ~180 MB

  convert_x<<<dim3(8192), 256, 0, stream>>>(x, xs);
  convert_w<<<dim3(8, 8, 3), 256, 0, stream>>>(Wq, Wk, Wv, wt);
  proj_kernel<<<dim3(34, 4, 12), 256, 0, stream>>>(xs, wt, bq, bk, bv, qs, ksb, vs);
  transpose_v<<<dim3(68, 8, 4), 256, 0, stream>>>(vs, vt);
  attn_kernel<<<dim3(SEQ / 64, BATCH), 512, 0, stream>>>(qs, ksb, vt, mask, out);
}

// Round 5
// 174.516 us; speedup vs baseline: 5.6963x; 1.8244x over previous
//
#include <hip/hip_runtime.h>
#include <math.h>
#include <stdint.h>

// Problem constants
#define BATCH 4
#define SEQ   4096
#define EMB   512
#define PADW  128
#define SPAD  (SEQ + 2*PADW)   // 4352
#define WIN   (3*PADW)         // 384 keys per window

static constexpr float SCALE = 0.04419417382415922f; // 1/sqrt(512)

typedef __attribute__((ext_vector_type(8))) short    s16x8;
typedef __attribute__((ext_vector_type(4))) short    s16x4;
typedef __attribute__((ext_vector_type(4))) float    f32x4;
typedef __attribute__((ext_vector_type(8))) _Float16 f16x8;

__device__ __forceinline__ unsigned short f2h(float x) {  // RNE f32->fp16
  _Float16 h = (_Float16)x;
  return __builtin_bit_cast(unsigned short, h);
}
__device__ __forceinline__ void gload16(const void* g, void* lds) {
  __builtin_amdgcn_global_load_lds(
      (const __attribute__((address_space(1))) uint32_t*)g,
      (__attribute__((address_space(3))) uint32_t*)lds, 16, 0, 0);
}
// LDS tile rows of 128B (8 x 16B slots), slot XOR-swizzled by (row&7).
// Inverse swizzle is applied on the global source address at staging time.
__device__ __forceinline__ f16x8 frag64(const unsigned short* base, int row, int slot) {
  return *(const f16x8*)((const char*)base + row * 128 + ((slot ^ (row & 7)) << 4));
}

// ---------------------------------------------------------------------------
// x [B,SEQ,512] f32 -> xh [B,SEQ,512] fp16
// ---------------------------------------------------------------------------
__global__ __launch_bounds__(256) void convert_x(const float* __restrict__ x,
                                                 unsigned short* __restrict__ xh) {
  size_t i = ((size_t)blockIdx.x * 256 + threadIdx.x) * 8;  // 8 elems/thread, grid exact
  float4 a = *(const float4*)&x[i];
  float4 c = *(const float4*)&x[i + 4];
  s16x8 o;
  o[0] = (short)f2h(a.x); o[1] = (short)f2h(a.y);
  o[2] = (short)f2h(a.z); o[3] = (short)f2h(a.w);
  o[4] = (short)f2h(c.x); o[5] = (short)f2h(c.y);
  o[6] = (short)f2h(c.z); o[7] = (short)f2h(c.w);
  *(s16x8*)&xh[i] = o;
}

// ---------------------------------------------------------------------------
// W [512 k,512 n] f32 (x3) -> wt [3, 512 n, 512 k] fp16 (transposed)
// ---------------------------------------------------------------------------
__global__ __launch_bounds__(256) void convert_w(const float* __restrict__ Wq,
                                                 const float* __restrict__ Wk,
                                                 const float* __restrict__ Wv,
                                                 unsigned short* __restrict__ wt) {
  const int w = blockIdx.z;
  const float* W = (w == 0) ? Wq : (w == 1) ? Wk : Wv;
  const int kt = blockIdx.x * 64, nt = blockIdx.y * 64;
  __shared__ float T[64][65];
  const int tid = threadIdx.x;
  {
    int r = tid >> 4, c4 = (tid & 15) * 4;
#pragma unroll
    for (int i = 0; i < 4; ++i) {
      float4 v = *(const float4*)&W[(size_t)(kt + r + 16 * i) * EMB + nt + c4];
      T[r + 16 * i][c4 + 0] = v.x;
      T[r + 16 * i][c4 + 1] = v.y;
      T[r + 16 * i][c4 + 2] = v.z;
      T[r + 16 * i][c4 + 3] = v.w;
    }
  }
  __syncthreads();
  {
    int n = tid >> 2, k0 = (tid & 3) * 16;
    __align__(16) unsigned short hb[16];
#pragma unroll
    for (int j = 0; j < 16; ++j) hb[j] = f2h(T[k0 + j][n]);
    size_t base = ((size_t)w * EMB + nt + n) * EMB;
    *(s16x8*)&wt[base + kt + k0]     = *(s16x8*)&hb[0];
    *(s16x8*)&wt[base + kt + k0 + 8] = *(s16x8*)&hb[8];
  }
}

// ---------------------------------------------------------------------------
// Projection GEMM (fp16 MFMA): out = ext(x) @ W + b for q,k,v.
// 128x128 tile, 4 waves, BK=64, global_load_lds(16B), XOR-swizzled LDS.
// w==2 (V) epilogue writes vt TRANSPOSED [B,512 e,SPAD t] via LDS staging.
// grid (34, 4, 12); XCD-swizzled (1632 = 8*204).
// ---------------------------------------------------------------------------
__global__ __launch_bounds__(256) void proj_kernel(
    const unsigned short* __restrict__ xh,  // [B,SEQ,512]
    const unsigned short* __restrict__ wt,  // [3,512,512]
    const float* __restrict__ bq, const float* __restrict__ bk, const float* __restrict__ bv,
    unsigned short* __restrict__ qh,   // [B,SPAD,512]
    unsigned short* __restrict__ kh,   // [B,SPAD,512]
    unsigned short* __restrict__ vt)   // [B,512,SPAD] (transposed!)
{
  int linear = blockIdx.x + 34 * (blockIdx.y + 4 * blockIdx.z);
  linear = (linear & 7) * 204 + (linear >> 3);   // bijective XCD chunking
  const int mt = linear % 34;
  const int nt = (linear / 34) & 3;
  const int z  = linear / 136;
  const int b = z / 3, w = z % 3;
  const float* bias = (w == 0) ? bq : (w == 1) ? bk : bv;
  const int tid = threadIdx.x, lane = tid & 63, wid = tid >> 6;
  const int t0 = mt * 128, n0 = nt * 128;

  if (mt == 0 || mt == 33) {  // all-pad tiles: Linear(0) = bias
    if (w < 2) {
      unsigned short* om = (w == 0) ? qh : kh;
      for (int i = tid; i < 128 * 128; i += 256) {
        int r = i >> 7, n = i & 127;
        om[((size_t)b * SPAD + t0 + r) * EMB + n0 + n] = f2h(bias[n0 + n]);
      }
    } else {
      for (int i = tid; i < 128 * 128; i += 256) {
        int e = i >> 7, t = i & 127;
        vt[((size_t)b * EMB + n0 + e) * SPAD + t0 + t] = f2h(bias[n0 + e]);
      }
    }
    return;
  }

  __shared__ __align__(16) unsigned short smem[17408];  // 34816 B
  unsigned short* At = smem;          // [128 m][64 k] swz (16 KB)
  unsigned short* Bt = smem + 8192;   // [128 n][64 k] swz (16 KB)

  f32x4 acc[4][4];
#pragma unroll
  for (int i = 0; i < 4; ++i)
#pragma unroll
    for (int j = 0; j < 4; ++j) acc[i][j] = (f32x4){0.f, 0.f, 0.f, 0.f};

  const int xr0 = (mt - 1) * 128;
  const int wm = wid >> 1, wn = wid & 1;

  for (int kt = 0; kt < EMB; kt += 64) {
#pragma unroll
    for (int i = 0; i < 4; ++i) {  // A tile: 1024 16B chunks
      int c = wid * 256 + i * 64 + lane;
      int m = c >> 3, sl = (c & 7) ^ (m & 7);
      gload16(xh + ((size_t)b * SEQ + xr0 + m) * EMB + kt + sl * 8,
              (char*)At + (wid * 256 + i * 64) * 16);
    }
#pragma unroll
    for (int i = 0; i < 4; ++i) {  // B tile
      int c = wid * 256 + i * 64 + lane;
      int n = c >> 3, sl = (c & 7) ^ (n & 7);
      gload16(wt + ((size_t)w * EMB + n0 + n) * EMB + kt + sl * 8,
              (char*)Bt + (wid * 256 + i * 64) * 16);
    }
    __syncthreads();
#pragma unroll
    for (int kk = 0; kk < 2; ++kk) {
      f16x8 af[4], bfr[4];
#pragma unroll
      for (int f = 0; f < 4; ++f)
        af[f] = frag64(At, wm * 64 + f * 16 + (lane & 15), kk * 4 + (lane >> 4));
#pragma unroll
      for (int f = 0; f < 4; ++f)
        bfr[f] = frag64(Bt, wn * 64 + f * 16 + (lane & 15), kk * 4 + (lane >> 4));
#pragma unroll
      for (int fm = 0; fm < 4; ++fm)
#pragma unroll
        for (int fn = 0; fn < 4; ++fn)
          acc[fm][fn] = __builtin_amdgcn_mfma_f32_16x16x32_f16(af[fm], bfr[fn], acc[fm][fn], 0, 0, 0);
    }
    __syncthreads();
  }

  if (w < 2) {  // q/k: direct row-major store
    unsigned short* om = (w == 0) ? qh : kh;
#pragma unroll
    for (int fm = 0; fm < 4; ++fm) {
      int t = t0 + wm * 64 + fm * 16 + ((lane >> 4) << 2);
#pragma unroll
      for (int fn = 0; fn < 4; ++fn) {
        int n = n0 + wn * 64 + fn * 16 + (lane & 15);
        float bsv = bias[n];
#pragma unroll
        for (int r = 0; r < 4; ++r)
          om[((size_t)b * SPAD + t + r) * EMB + n] = f2h(acc[fm][fn][r] + bsv);
      }
    }
  } else {  // V: transpose via LDS, write vt[e][t]
    unsigned short* T = smem;  // [128 e][136 t] (stride 136 -> 272B, 16B-mult)
    // last __syncthreads of K-loop guarantees At/Bt reads are done
#pragma unroll
    for (int fm = 0; fm < 4; ++fm) {
      int tl = wm * 64 + fm * 16 + ((lane >> 4) << 2);
#pragma unroll
      for (int fn = 0; fn < 4; ++fn) {
        int el = wn * 64 + fn * 16 + (lane & 15);
        float bsv = bias[n0 + el];
        s16x4 pk;
#pragma unroll
        for (int r = 0; r < 4; ++r) pk[r] = (short)f2h(acc[fm][fn][r] + bsv);
        *(s16x4*)&T[el * 136 + tl] = pk;   // 8B store, aligned
      }
    }
    __syncthreads();
#pragma unroll
    for (int it = 0; it < 8; ++it) {  // 2048 16B chunks
      int c = it * 256 + tid;
      int e = c >> 4, t8 = (c & 15) * 8;
      s16x8 vchunk = *(s16x8*)&T[e * 136 + t8];
      *(s16x8*)&vt[((size_t)b * EMB + n0 + e) * SPAD + t0 + t8] = vchunk;
    }
  }
}

// ---------------------------------------------------------------------------
// Banded attention, fp16 MFMA. One wg = 64 queries, 8 waves (512 thr).
// Phase A: S^T[384,64] = K[384,512] . Q^T -> regs
// Phase B: mask + softmax (wave shuffle + LDS cross-wave), P -> LDS fp16
// Phase C: O[64,512] = P[64,384] . V[384,512], V staged from transposed vt.
// grid (64, 4) XCD-swizzled (256 = 8*32).
// ---------------------------------------------------------------------------
__global__ __launch_bounds__(512) void attn_kernel(
    const unsigned short* __restrict__ qh,
    const unsigned short* __restrict__ kh,
    const unsigned short* __restrict__ vt,
    const int* __restrict__ mask,
    float* __restrict__ out) {
  int linear = blockIdx.x + 64 * blockIdx.y;
  linear = (linear & 7) * 32 + (linear >> 3);
  const int b  = linear >> 6;
  const int s0 = (linear & 63) * 64;
  const int nb = s0 >> 7, o = s0 & 127;  // o in {0, 64}
  const int t0 = nb * 128;
  const int tid = threadIdx.x, lane = tid & 63, wid = tid >> 6;

  __shared__ __align__(16) char smem[88 * 1024];
  unsigned short* Kt = (unsigned short*)smem;                 // [384][64] swz / later P [64][384] swz
  unsigned short* Qt = (unsigned short*)(smem + 48 * 1024);   // [64][64] swz
  float* red  = (float*)(smem + 48 * 1024);                   // aliases Qt (dead after phase A)
  float* red2 = (float*)(smem + 48 * 1024 + 2048);
  float* invl = (float*)(smem + 48 * 1024 + 4096);            // [64]
  float* Pm   = (float*)(smem + 48 * 1024 + 4352);            // [384]
  unsigned short* Vt = (unsigned short*)(smem + 56 * 1024);   // [512][32] swz

  // ---- phase A: S^T = K.Q^T ----
  f32x4 accS[3][4];
#pragma unroll
  for (int i = 0; i < 3; ++i)
#pragma unroll
    for (int j = 0; j < 4; ++j) accS[i][j] = (f32x4){0.f, 0.f, 0.f, 0.f};

  for (int kt = 0; kt < EMB; kt += 64) {
#pragma unroll
    for (int i = 0; i < 6; ++i) {  // K tile: 3072 chunks
      int c = wid * 384 + i * 64 + lane;
      int r = c >> 3, sl = (c & 7) ^ (r & 7);
      gload16(kh + ((size_t)b * SPAD + t0 + r) * EMB + kt + sl * 8,
              (char*)Kt + (wid * 384 + i * 64) * 16);
    }
    {  // Q tile: 512 chunks
      int c = wid * 64 + lane;
      int r = c >> 3, sl = (c & 7) ^ (r & 7);
      gload16(qh + ((size_t)b * SPAD + PADW + s0 + r) * EMB + kt + sl * 8,
              (char*)Qt + (wid * 64) * 16);
    }
    __syncthreads();
#pragma unroll
    for (int kk = 0; kk < 2; ++kk) {
      f16x8 af[3], bfq[4];
#pragma unroll
      for (int f = 0; f < 3; ++f)
        af[f] = frag64(Kt, wid * 48 + f * 16 + (lane & 15), kk * 4 + (lane >> 4));
#pragma unroll
      for (int f = 0; f < 4; ++f)
        bfq[f] = frag64(Qt, f * 16 + (lane & 15), kk * 4 + (lane >> 4));
#pragma unroll
      for (int fk = 0; fk < 3; ++fk)
#pragma unroll
        for (int fq = 0; fq < 4; ++fq)
          accS[fk][fq] = __builtin_amdgcn_mfma_f32_16x16x32_f16(af[fk], bfq[fq], accS[fk][fq], 0, 0, 0);
    }
    __syncthreads();
  }

  // key-side mask (pads unmasked = 1)
  for (int k = tid; k < WIN; k += 512) {
    int t = t0 + k;
    Pm[k] = (t >= PADW && t < SEQ + PADW) ? (float)mask[(size_t)b * SEQ + (t - PADW)] : 1.f;
  }
  __syncthreads();

  // ---- phase B: mask + softmax ----
  float mx[4] = {-INFINITY, -INFINITY, -INFINITY, -INFINITY};
#pragma unroll
  for (int fk = 0; fk < 3; ++fk)
#pragma unroll
    for (int fq = 0; fq < 4; ++fq)
#pragma unroll
      for (int r = 0; r < 4; ++r) {
        int k = wid * 48 + fk * 16 + ((lane >> 4) << 2) + r;
        int p = o + fq * 16 + (lane & 15);  // query pos in block
        float v;
        if (k < p || k > p + 2 * PADW) v = -INFINITY;                 // band
        else v = (Pm[k] == 0.f) ? -1e9f : accS[fk][fq][r] * SCALE;    // pm mask
        accS[fk][fq][r] = v;
        mx[fq] = fmaxf(mx[fq], v);
      }
#pragma unroll
  for (int fq = 0; fq < 4; ++fq) {
    mx[fq] = fmaxf(mx[fq], __shfl_xor(mx[fq], 16));
    mx[fq] = fmaxf(mx[fq], __shfl_xor(mx[fq], 32));
  }
  if (lane < 16) {
#pragma unroll
    for (int fq = 0; fq < 4; ++fq) red[wid * 64 + fq * 16 + lane] = mx[fq];
  }
  __syncthreads();
  float M[4];
#pragma unroll
  for (int fq = 0; fq < 4; ++fq) {
    float m = -INFINITY;
#pragma unroll
    for (int ww = 0; ww < 8; ++ww) m = fmaxf(m, red[ww * 64 + fq * 16 + (lane & 15)]);
    M[fq] = m;
  }
  float sm[4] = {0.f, 0.f, 0.f, 0.f};
#pragma unroll
  for (int fk = 0; fk < 3; ++fk)
#pragma unroll
    for (int fq = 0; fq < 4; ++fq)
#pragma unroll
      for (int r = 0; r < 4; ++r) {
        float pv = __expf(accS[fk][fq][r] - M[fq]);
        accS[fk][fq][r] = pv;
        sm[fq] += pv;
      }
#pragma unroll
  for (int fq = 0; fq < 4; ++fq) {
    sm[fq] += __shfl_xor(sm[fq], 16);
    sm[fq] += __shfl_xor(sm[fq], 32);
  }
  if (lane < 16) {
#pragma unroll
    for (int fq = 0; fq < 4; ++fq) red2[wid * 64 + fq * 16 + lane] = sm[fq];
  }
  __syncthreads();
  {
    float L[4];
#pragma unroll
    for (int fq = 0; fq < 4; ++fq) {
      float s = 0.f;
#pragma unroll
      for (int ww = 0; ww < 8; ++ww) s += red2[ww * 64 + fq * 16 + (lane & 15)];
      L[fq] = s;
    }
    if (wid == 0 && lane < 16) {
#pragma unroll
      for (int fq = 0; fq < 4; ++fq) invl[fq * 16 + lane] = 1.f / L[fq];
    }
  }
  // write P (fp16, unnormalized) to LDS: [64 q][384 k], 16B-slot XOR (q&7)
#pragma unroll
  for (int fk = 0; fk < 3; ++fk)
#pragma unroll
    for (int fq = 0; fq < 4; ++fq) {
      int k0 = wid * 48 + fk * 16 + ((lane >> 4) << 2);
      int q = fq * 16 + (lane & 15);
      s16x4 pk;
      pk[0] = (short)f2h(accS[fk][fq][0]);
      pk[1] = (short)f2h(accS[fk][fq][1]);
      pk[2] = (short)f2h(accS[fk][fq][2]);
      pk[3] = (short)f2h(accS[fk][fq][3]);
      int sl = k0 >> 3;
      *(s16x4*)((char*)Kt + q * 768 + (((sl ^ (q & 7))) << 4) + ((k0 & 7) << 1)) = pk;
    }
  __syncthreads();

  // ---- phase C: O = P.V ----
  f32x4 accO[4][4];
#pragma unroll
  for (int i = 0; i < 4; ++i)
#pragma unroll
    for (int j = 0; j < 4; ++j) accO[i][j] = (f32x4){0.f, 0.f, 0.f, 0.f};

  for (int kb = 0; kb < WIN; kb += 32) {
#pragma unroll
    for (int i = 0; i < 4; ++i) {  // Vt tile [512 e][32 k]: 2048 chunks
      int c = wid * 256 + i * 64 + lane;
      int e = c >> 2, sl = (c & 3) ^ (e & 3);
      gload16(vt + ((size_t)b * EMB + e) * SPAD + t0 + kb + sl * 8,
              (char*)Vt + (wid * 256 + i * 64) * 16);
    }
    __syncthreads();
    f16x8 pa[4], vb[4];
#pragma unroll
    for (int fq = 0; fq < 4; ++fq) {
      int q = fq * 16 + (lane & 15);
      int sl = (kb + ((lane >> 4) << 3)) >> 3;
      pa[fq] = *(const f16x8*)((const char*)Kt + q * 768 + ((sl ^ (q & 7)) << 4));
    }
#pragma unroll
    for (int fe = 0; fe < 4; ++fe) {
      int e = wid * 64 + fe * 16 + (lane & 15);
      int sl = (lane >> 4) ^ (e & 3);
      vb[fe] = *(const f16x8*)((const char*)Vt + e * 64 + (sl << 4));
    }
#pragma unroll
    for (int fq = 0; fq < 4; ++fq)
#pragma unroll
      for (int fe = 0; fe < 4; ++fe)
        accO[fq][fe] = __builtin_amdgcn_mfma_f32_16x16x32_f16(pa[fq], vb[fe], accO[fq][fe], 0, 0, 0);
    __syncthreads();
  }

  // epilogue: normalize by 1/l, zero masked queries
#pragma unroll
  for (int fq = 0; fq < 4; ++fq)
#pragma unroll
    for (int r = 0; r < 4; ++r) {
      int q = fq * 16 + ((lane >> 4) << 2) + r;
      float sc = invl[q] * ((Pm[PADW + o + q] != 0.f) ? 1.f : 0.f);
#pragma unroll
      for (int fe = 0; fe < 4; ++fe) {
        int e = wid * 64 + fe * 16 + (lane & 15);
        out[((size_t)b * SEQ + s0 + q) * EMB + e] = accO[fq][fe][r] * sc;
      }
    }
}

// ---------------------------------------------------------------------------
extern "C" void kernel_launch(void* const* d_in, const int* in_sizes, int n_in,
                              void* d_out, int out_size, void* d_ws, size_t ws_size,
                              hipStream_t stream) {
  const float* x  = (const float*)d_in[0];
  const int* mask = (const int*)d_in[1];
  const float* Wq = (const float*)d_in[2];
  const float* bq = (const float*)d_in[3];
  const float* Wk = (const float*)d_in[4];
  const float* bk = (const float*)d_in[5];
  const float* Wv = (const float*)d_in[6];
  const float* bv = (const float*)d_in[7];
  float* out = (float*)d_out;

  char* ws = (char*)d_ws;
  unsigned short* xh = (unsigned short*)ws;               // 16,777,216 B [B,SEQ,512]
  unsigned short* wt = (unsigned short*)(ws + 16777216);  //  1,572,864 B [3,512,512]
  unsigned short* qh = (unsigned short*)(ws + 18350080);  // 17,825,792 B [B,SPAD,512]
  unsigned short* kh = (unsigned short*)(ws + 36175872);  // 17,825,792 B [B,SPAD,512]
  unsigned short* vt = (unsigned short*)(ws + 54001664);  // 17,825,792 B [B,512,SPAD] -> ~72 MB

  convert_x<<<dim3(4096), 256, 0, stream>>>(x, xh);
  convert_w<<<dim3(8, 8, 3), 256, 0, stream>>>(Wq, Wk, Wv, wt);
  proj_kernel<<<dim3(34, 4, 12), 256, 0, stream>>>(xh, wt, bq, bk, bv, qh, kh, vt);
  attn_kernel<<<dim3(SEQ / 64, BATCH), 512, 0, stream>>>(qh, kh, vt, mask, out);
}